// Round 7
// baseline (572.011 us; speedup 1.0000x reference)
//
#include <hip/hip_runtime.h>
#include <math.h>

#define NB 8
#define NP 2048
#define CHUNK 32            // src pts per block
#define NCHK  64            // chunks per batch
#define GRID_ITER 512       // NB * NCHK
#define TOLF 1e-4f
#define EPSF 1e-12f

// identical fmaf structure everywhere => bit-identical transformed points
__device__ inline float3 xform_pt(const float* __restrict__ T,
                                  float x, float y, float z) {
    float3 r;
    r.x = fmaf(T[0], x, fmaf(T[1], y, fmaf(T[2], z, T[9])));
    r.y = fmaf(T[3], x, fmaf(T[4], y, fmaf(T[5], z, T[10])));
    r.z = fmaf(T[6], x, fmaf(T[7], y, fmaf(T[8], z, T[11])));
    return r;
}

// ---------------- 3x3 Kabsch: fp64 sums -> fp32 Jacobi SVD -> fp64 compose ----
__device__ void kabsch3x3(const double Spq[9], const double Sp[3], const double Sq[3],
                          double R[9], double t[3]) {
    const double invN = 1.0 / (double)NP;
    double cs[3], ct[3];
#pragma unroll
    for (int i = 0; i < 3; ++i) { cs[i] = Sp[i] * invN; ct[i] = Sq[i] * invN; }
    double Hd[9];
#pragma unroll
    for (int i = 0; i < 3; ++i)
#pragma unroll
        for (int j = 0; j < 3; ++j)
            Hd[i * 3 + j] = Spq[i * 3 + j] - (double)NP * cs[i] * ct[j];

    // one-sided Jacobi on columns, fp32, fixed 10 sweeps (HW rcp/sqrt)
    float Bc[3][3], V[3][3];
#pragma unroll
    for (int j = 0; j < 3; ++j)
#pragma unroll
        for (int i = 0; i < 3; ++i) {
            Bc[j][i] = (float)Hd[i * 3 + j];
            V[j][i]  = (i == j) ? 1.0f : 0.0f;
        }
    for (int sweep = 0; sweep < 10; ++sweep) {
        for (int p = 0; p < 2; ++p)
            for (int q = p + 1; q < 3; ++q) {
                float app = 0.f, aqq = 0.f, apq = 0.f;
#pragma unroll
                for (int i = 0; i < 3; ++i) {
                    app = fmaf(Bc[p][i], Bc[p][i], app);
                    aqq = fmaf(Bc[q][i], Bc[q][i], aqq);
                    apq = fmaf(Bc[p][i], Bc[q][i], apq);
                }
                if (fabsf(apq) > 1e-20f) {
                    float tau = (aqq - app) / (2.0f * apq);
                    float tt  = (tau >= 0.f ? 1.0f : -1.0f) /
                                (fabsf(tau) + sqrtf(fmaf(tau, tau, 1.0f)));
                    float c   = 1.0f / sqrtf(fmaf(tt, tt, 1.0f));
                    float sn  = c * tt;
#pragma unroll
                    for (int i = 0; i < 3; ++i) {
                        float bp = Bc[p][i], bq = Bc[q][i];
                        Bc[p][i] = c * bp - sn * bq;
                        Bc[q][i] = sn * bp + c * bq;
                        float vp = V[p][i], vq = V[q][i];
                        V[p][i] = c * vp - sn * vq;
                        V[q][i] = sn * vp + c * vq;
                    }
                }
            }
    }
    float sv[3], U[3][3];
#pragma unroll
    for (int j = 0; j < 3; ++j) {
        sv[j] = sqrtf(Bc[j][0] * Bc[j][0] + Bc[j][1] * Bc[j][1] + Bc[j][2] * Bc[j][2]);
        float inv = sv[j] > 0.f ? 1.0f / sv[j] : 0.f;
#pragma unroll
        for (int i = 0; i < 3; ++i) U[j][i] = Bc[j][i] * inv;
    }
    double detH = Hd[0] * (Hd[4] * Hd[8] - Hd[5] * Hd[7])
                - Hd[1] * (Hd[3] * Hd[8] - Hd[5] * Hd[6])
                + Hd[2] * (Hd[3] * Hd[7] - Hd[4] * Hd[6]);
    float d = (detH >= 0.0) ? 1.0f : -1.0f;
    int o[3] = {0, 1, 2};
    if (sv[o[0]] < sv[o[1]]) { int tmp = o[0]; o[0] = o[1]; o[1] = tmp; }
    if (sv[o[0]] < sv[o[2]]) { int tmp = o[0]; o[0] = o[2]; o[2] = tmp; }
    if (sv[o[1]] < sv[o[2]]) { int tmp = o[1]; o[1] = o[2]; o[2] = tmp; }
    float sg[3] = {1.0f, 1.0f, d};
#pragma unroll
    for (int i = 0; i < 3; ++i)
#pragma unroll
        for (int j = 0; j < 3; ++j) {
            float acc = 0.0f;
#pragma unroll
            for (int k = 0; k < 3; ++k) acc += sg[k] * V[o[k]][i] * U[o[k]][j];
            R[i * 3 + j] = (double)acc;
        }
#pragma unroll
    for (int i = 0; i < 3; ++i)
        t[i] = ct[i] - (R[i * 3 + 0] * cs[0] + R[i * 3 + 1] * cs[1] + R[i * 3 + 2] * cs[2]);
}

// ---------------- init ----------------
__global__ __launch_bounds__(256) void icp_init(double* __restrict__ Tc,
                                                float* __restrict__ TcF,
                                                float* __restrict__ err,
                                                int* __restrict__ done,
                                                unsigned int* __restrict__ ticket) {
    int g = threadIdx.x;
    if (g < NB) {
        double* T = Tc + g * 12;
        float*  F = TcF + g * 12;
#pragma unroll
        for (int k = 0; k < 12; ++k) { T[k] = 0.0; F[k] = 0.0f; }
        T[0] = T[4] = T[8] = 1.0;
        F[0] = F[4] = F[8] = 1.0f;
        err[g] = 0.0f;
    }
    if (g >= 16 && g < 26) ticket[g - 16] = 0u;
    if (g == 26) *done = 0;
}

// ---------------- one full ICP iteration ----------------
// grid: 512 blocks = batch(8) x src-chunk(64 of 32 pts), 256 threads, 2 blocks/CU.
// thread = (g = tid>>5: 4 src pts, slice = tid&31: 64 targets).
__global__ __launch_bounds__(256, 2) void icp_iter(
        const float* __restrict__ psrc, const float* __restrict__ ptgt,
        double* __restrict__ partial,
        double* __restrict__ Tc, float* __restrict__ TcF,
        float* __restrict__ err, int* __restrict__ done,
        unsigned int* __restrict__ ticket, float* __restrict__ out, int it) {
    if (*done) return;

    __shared__ float4 tg[2080];        // padded: idx = j + (j>>6); slice base = slice*65
    __shared__ float4 ps[CHUNK];       // transformed src pts (x,y,z,|P|^2)
    __shared__ float2 comb[32][34];    // [slice][src] winners, padded rows
    __shared__ double sred[NB][16];
    __shared__ int lastflag;

    const int tid   = threadIdx.x;
    const int blk   = blockIdx.x;
    const int b     = blk >> 6;        // batch
    const int sc    = blk & 63;        // src chunk
    const int slice = tid & 31;        // target slice (64 targets)
    const int g     = tid >> 5;        // src group (4 pts)

    // stage all 2048 targets for this batch (padded layout)
    const float* tb = ptgt + b * NP * 3;
    for (int j = tid; j < NP; j += 256) {
        float tx = tb[3 * j + 0], ty = tb[3 * j + 1], tz = tb[3 * j + 2];
        tg[j + (j >> 6)] = make_float4(tx, ty, tz,
                                       0.5f * (tx * tx + ty * ty + tz * tz));
    }
    // stage this chunk's 32 src points, transformed once (bit-identical reuse)
    if (tid < CHUNK) {
        const float* pp = psrc + (b * NP + sc * CHUNK + tid) * 3;
        float3 P = xform_pt(TcF + b * 12, pp[0], pp[1], pp[2]);
        ps[tid] = make_float4(P.x, P.y, P.z, P.x * P.x + P.y * P.y + P.z * P.z);
    }
    __syncthreads();

    // 4 src pts in registers; scan 64 targets of this slice
    float sx[4], sy[4], sz[4], sm[4];
    int jm[4];
#pragma unroll
    for (int k = 0; k < 4; ++k) {
        float4 P = ps[g * 4 + k];
        sx[k] = P.x; sy[k] = P.y; sz[k] = P.z;
        sm[k] = INFINITY; jm[k] = 0;
    }
    const int base = slice * 65, jbase = slice * 64;
#pragma unroll 4
    for (int i = 0; i < 64; ++i) {
        float4 t = tg[base + i];
        int j = jbase + i;
#pragma unroll
        for (int k = 0; k < 4; ++k) {
            float s = fmaf(-sx[k], t.x, fmaf(-sy[k], t.y, fmaf(-sz[k], t.z, t.w)));
            if (s < sm[k]) { sm[k] = s; jm[k] = j; }   // ascending j: first-min
        }
    }
#pragma unroll
    for (int k = 0; k < 4; ++k)
        comb[slice][g * 4 + k] = make_float2(sm[k], __int_as_float(jm[k]));
    __syncthreads();

    // lanes 0-31 of wave 0: merge 32 slices (ascending => exact first-min tie-break)
    if (tid < CHUNK) {
        float fb = INFINITY; int fj = 0;
#pragma unroll 8
        for (int q = 0; q < 32; ++q) {
            float2 e = comb[q][tid];
            if (e.x < fb) { fb = e.x; fj = __float_as_int(e.y); }
        }
        float4 P = ps[tid];
        float d2 = fmaf(2.0f, fb, P.w);
        float dist = sqrtf(fmaxf(d2, EPSF));
        float4 Q = tg[fj + (fj >> 6)];

        double v[16];
        v[0] = dist;
        v[1] = P.x; v[2] = P.y; v[3] = P.z;
        v[4] = Q.x; v[5] = Q.y; v[6] = Q.z;
        v[7]  = (double)P.x * Q.x; v[8]  = (double)P.x * Q.y; v[9]  = (double)P.x * Q.z;
        v[10] = (double)P.y * Q.x; v[11] = (double)P.y * Q.y; v[12] = (double)P.y * Q.z;
        v[13] = (double)P.z * Q.x; v[14] = (double)P.z * Q.y; v[15] = (double)P.z * Q.z;
        // reduce over 32 lanes (garbage from lanes>=32 never reaches lane 0)
#pragma unroll
        for (int k = 0; k < 16; ++k) {
            double x = v[k];
            x += __shfl_down(x, 16);
            x += __shfl_down(x, 8);
            x += __shfl_down(x, 4);
            x += __shfl_down(x, 2);
            x += __shfl_down(x, 1);
            v[k] = x;
        }
        if (tid == 0) {
            double* dst = partial + blk * 16;
#pragma unroll
            for (int k = 0; k < 16; ++k) dst[k] = v[k];
        }
    }

    // ---- ticket: last block of this iteration runs the tail ----
    __threadfence();
    __syncthreads();
    if (tid == 0) {
        unsigned old = atomicAdd(&ticket[it], 1u);
        lastflag = (old == GRID_ITER - 1) ? 1 : 0;
    }
    __syncthreads();
    if (!lastflag) return;
    __threadfence();

    // ================= tail (single block) =================
    {
        int tb2 = tid >> 5;          // batch (0..7)
        int c32 = tid & 31;          // chunk pair c32, c32+32
        double acc[16];
        const double* p1 = partial + ((tb2 * NCHK) + c32) * 16;
        const double* p2 = partial + ((tb2 * NCHK) + 32 + c32) * 16;
#pragma unroll
        for (int k = 0; k < 16; ++k) {
            double a = __hip_atomic_load(p1 + k, __ATOMIC_RELAXED,
                                         __HIP_MEMORY_SCOPE_AGENT);
            double bq = __hip_atomic_load(p2 + k, __ATOMIC_RELAXED,
                                          __HIP_MEMORY_SCOPE_AGENT);
            acc[k] = a + bq;
        }
#pragma unroll
        for (int k = 0; k < 16; ++k) {
            double x = acc[k];
            x += __shfl_down(x, 16);
            x += __shfl_down(x, 8);
            x += __shfl_down(x, 4);
            x += __shfl_down(x, 2);
            x += __shfl_down(x, 1);
            if (c32 == 0) sred[tb2][k] = x;
        }
    }
    __syncthreads();

    if (tid < 64) {
        double s[16];
        float errnew = 0.0f;
        bool conv = true;
        if (tid < NB) {
#pragma unroll
            for (int k = 0; k < 16; ++k) s[k] = sred[tid][k];
            errnew = (float)(s[0] * (1.0 / (double)NP));
            conv = fabsf(errnew - err[tid]) < TOLF;
        }
        unsigned long long mm = __ballot(conv);
        int done_new = ((mm & 0xFFull) == 0xFFull) ? 1 : 0;
        if (tid == 0 && done_new) *done = 1;

        if (tid < NB) {
            double* T = Tc + tid * 12;
            double To[12];
#pragma unroll
            for (int k = 0; k < 12; ++k) To[k] = T[k];

            if (!done_new) {
                err[tid] = errnew;
                double R[9], t[3];
                kabsch3x3(&s[7], &s[1], &s[4], R, t);
                double Rn[12];
#pragma unroll
                for (int i = 0; i < 3; ++i) {
#pragma unroll
                    for (int j = 0; j < 3; ++j)
                        Rn[i * 3 + j] = R[i * 3 + 0] * To[0 + j]
                                      + R[i * 3 + 1] * To[3 + j]
                                      + R[i * 3 + 2] * To[6 + j];
                    Rn[9 + i] = R[i * 3 + 0] * To[9] + R[i * 3 + 1] * To[10]
                              + R[i * 3 + 2] * To[11] + t[i];
                }
                float* F = TcF + tid * 12;
#pragma unroll
                for (int k = 0; k < 12; ++k) { T[k] = Rn[k]; F[k] = (float)Rn[k]; To[k] = Rn[k]; }
            }

            // out = current cumulative transform (Kabsch(psrc, T(psrc)) == T)
            float* o = out + tid * 12;
#pragma unroll
            for (int i = 0; i < 3; ++i) {
#pragma unroll
                for (int j = 0; j < 3; ++j) o[i * 4 + j] = (float)To[i * 3 + j];
                o[i * 4 + 3] = (float)To[9 + i];
            }
        }
    }
}

extern "C" void kernel_launch(void* const* d_in, const int* in_sizes, int n_in,
                              void* d_out, int out_size, void* d_ws, size_t ws_size,
                              hipStream_t stream) {
    const float* psrc = (const float*)d_in[0];
    const float* ptgt = (const float*)d_in[1];
    float* out = (float*)d_out;

    char* ws = (char*)d_ws;
    size_t off = 0;
    double* partial = (double*)(ws + off); off += (size_t)GRID_ITER * 16 * sizeof(double); // 64KB
    double* Tc   = (double*)(ws + off); off += NB * 12 * sizeof(double);
    float*  TcF  = (float*)(ws + off);  off += NB * 12 * sizeof(float);
    float*  err  = (float*)(ws + off);  off += 32;
    int*    done = (int*)(ws + off);    off += 16;
    unsigned int* ticket = (unsigned int*)(ws + off);

    icp_init<<<1, 256, 0, stream>>>(Tc, TcF, err, done, ticket);

    for (int it = 0; it < 10; ++it) {
        icp_iter<<<GRID_ITER, 256, 0, stream>>>(psrc, ptgt, partial, Tc, TcF,
                                                err, done, ticket, out, it);
    }
}

// Round 8
// 259.817 us; speedup vs baseline: 2.2016x; 2.2016x over previous
//
#include <hip/hip_runtime.h>
#include <math.h>

#define NB 8
#define NP 2048
#define GRID_ITER 256   // 8 batches * 32 src-chunks of 64
#define TOLF 1e-4f
#define EPSF 1e-12f

// identical fmaf structure everywhere => bit-identical transformed points
__device__ inline float3 xform_pt(const float* __restrict__ T,
                                  float x, float y, float z) {
    float3 r;
    r.x = fmaf(T[0], x, fmaf(T[1], y, fmaf(T[2], z, T[9])));
    r.y = fmaf(T[3], x, fmaf(T[4], y, fmaf(T[5], z, T[10])));
    r.z = fmaf(T[6], x, fmaf(T[7], y, fmaf(T[8], z, T[11])));
    return r;
}

// ---------------- 3x3 Kabsch (double, one-sided Jacobi SVD) ----------------
__device__ void kabsch3x3(const double Spq[9], const double Sp[3], const double Sq[3],
                          double R[9], double t[3]) {
    const double invN = 1.0 / (double)NP;
    double cs[3], ct[3];
#pragma unroll
    for (int i = 0; i < 3; ++i) { cs[i] = Sp[i] * invN; ct[i] = Sq[i] * invN; }
    double H[9];
#pragma unroll
    for (int i = 0; i < 3; ++i)
#pragma unroll
        for (int j = 0; j < 3; ++j)
            H[i * 3 + j] = Spq[i * 3 + j] - (double)NP * cs[i] * ct[j];

    double Bc[3][3], V[3][3];
#pragma unroll
    for (int j = 0; j < 3; ++j)
#pragma unroll
        for (int i = 0; i < 3; ++i) {
            Bc[j][i] = H[i * 3 + j];
            V[j][i]  = (i == j) ? 1.0 : 0.0;
        }
    for (int sweep = 0; sweep < 16; ++sweep) {
        bool rotated = false;
        for (int p = 0; p < 2; ++p)
            for (int q = p + 1; q < 3; ++q) {
                double app = 0, aqq = 0, apq = 0;
#pragma unroll
                for (int i = 0; i < 3; ++i) {
                    app += Bc[p][i] * Bc[p][i];
                    aqq += Bc[q][i] * Bc[q][i];
                    apq += Bc[p][i] * Bc[q][i];
                }
                if (apq * apq > 1e-60 + 1e-28 * app * aqq) {
                    rotated = true;
                    double tau = (aqq - app) / (2.0 * apq);
                    double tt  = (tau >= 0 ? 1.0 : -1.0) / (fabs(tau) + sqrt(1.0 + tau * tau));
                    double c   = 1.0 / sqrt(1.0 + tt * tt);
                    double sn  = c * tt;
#pragma unroll
                    for (int i = 0; i < 3; ++i) {
                        double bp = Bc[p][i], bq = Bc[q][i];
                        Bc[p][i] = c * bp - sn * bq;
                        Bc[q][i] = sn * bp + c * bq;
                        double vp = V[p][i], vq = V[q][i];
                        V[p][i] = c * vp - sn * vq;
                        V[q][i] = sn * vp + c * vq;
                    }
                }
            }
        if (!rotated) break;
    }
    double sv[3], U[3][3];
#pragma unroll
    for (int j = 0; j < 3; ++j) {
        sv[j] = sqrt(Bc[j][0] * Bc[j][0] + Bc[j][1] * Bc[j][1] + Bc[j][2] * Bc[j][2]);
        double inv = sv[j] > 0.0 ? 1.0 / sv[j] : 0.0;
#pragma unroll
        for (int i = 0; i < 3; ++i) U[j][i] = Bc[j][i] * inv;
    }
    double detH = H[0] * (H[4] * H[8] - H[5] * H[7])
                - H[1] * (H[3] * H[8] - H[5] * H[6])
                + H[2] * (H[3] * H[7] - H[4] * H[6]);
    double d = (detH >= 0.0) ? 1.0 : -1.0;
    int o[3] = {0, 1, 2};
    if (sv[o[0]] < sv[o[1]]) { int tmp = o[0]; o[0] = o[1]; o[1] = tmp; }
    if (sv[o[0]] < sv[o[2]]) { int tmp = o[0]; o[0] = o[2]; o[2] = tmp; }
    if (sv[o[1]] < sv[o[2]]) { int tmp = o[1]; o[1] = o[2]; o[2] = tmp; }
    double sg[3] = {1.0, 1.0, d};
#pragma unroll
    for (int i = 0; i < 3; ++i)
#pragma unroll
        for (int j = 0; j < 3; ++j) {
            double acc = 0.0;
#pragma unroll
            for (int k = 0; k < 3; ++k) acc += sg[k] * V[o[k]][i] * U[o[k]][j];
            R[i * 3 + j] = acc;
        }
#pragma unroll
    for (int i = 0; i < 3; ++i)
        t[i] = ct[i] - (R[i * 3 + 0] * cs[0] + R[i * 3 + 1] * cs[1] + R[i * 3 + 2] * cs[2]);
}

// ---------------- init ----------------
__global__ __launch_bounds__(256) void icp_init(double* __restrict__ Tc,
                                                float* __restrict__ TcF,
                                                float* __restrict__ err,
                                                int* __restrict__ done,
                                                unsigned int* __restrict__ ticket) {
    int g = threadIdx.x;
    if (g < NB) {
        double* T = Tc + g * 12;
        float*  F = TcF + g * 12;
#pragma unroll
        for (int k = 0; k < 12; ++k) { T[k] = 0.0; F[k] = 0.0f; }
        T[0] = T[4] = T[8] = 1.0;
        F[0] = F[4] = F[8] = 1.0f;
        err[g] = 0.0f;
    }
    if (g >= 16 && g < 26) ticket[g - 16] = 0u;
    if (g == 26) *done = 0;
}

// ---------------- one full ICP iteration ----------------
// grid: 256 blocks = batch(8) x src-chunk(32 of 64 pts), 256 threads.
// thread = (src-group g = tid>>5: 8 pts, target-slice = tid&31: 64 targets).
// Cross-block comm: agent-scope (LLC) atomics only — NO cache-flushing fences.
__global__ __launch_bounds__(256, 2) void icp_iter(
        const float* __restrict__ psrc, const float* __restrict__ ptgt,
        double* __restrict__ partial,
        double* __restrict__ Tc, float* __restrict__ TcF,
        float* __restrict__ err, int* __restrict__ done,
        unsigned int* __restrict__ ticket, float* __restrict__ out, int it) {
    if (*done) return;

    __shared__ float4 tg[2080];        // padded: idx = j + (j>>6); slice stride 65
    __shared__ float4 ps[64];          // transformed src pts (x,y,z,|P|^2)
    __shared__ float2 comb[32][66];    // [slice][src] winners, padded rows
    __shared__ double sred[NB][16];
    __shared__ int lastflag;

    const int tid   = threadIdx.x;
    const int blk   = blockIdx.x;
    const int b     = blk >> 5;        // batch
    const int sc    = blk & 31;        // src chunk
    const int slice = tid & 31;        // target slice (64 targets)
    const int g     = tid >> 5;        // src group (8 pts)

    // stage all 2048 targets for this batch (padded layout)
    const float* tb = ptgt + b * NP * 3;
    for (int j = tid; j < NP; j += 256) {
        float tx = tb[3 * j + 0], ty = tb[3 * j + 1], tz = tb[3 * j + 2];
        tg[j + (j >> 6)] = make_float4(tx, ty, tz,
                                       0.5f * (tx * tx + ty * ty + tz * tz));
    }
    // stage this chunk's 64 src points, transformed once (bit-identical reuse)
    if (tid < 64) {
        const float* pp = psrc + (b * NP + sc * 64 + tid) * 3;
        float3 P = xform_pt(TcF + b * 12, pp[0], pp[1], pp[2]);
        ps[tid] = make_float4(P.x, P.y, P.z, P.x * P.x + P.y * P.y + P.z * P.z);
    }
    __syncthreads();

    // 8 src pts in registers; scan 64 targets of this slice
    float sx[8], sy[8], sz[8], sm[8];
    int jm[8];
#pragma unroll
    for (int k = 0; k < 8; ++k) {
        float4 P = ps[g * 8 + k];
        sx[k] = P.x; sy[k] = P.y; sz[k] = P.z;
        sm[k] = INFINITY; jm[k] = 0;
    }
    const int base = slice * 65, jbase = slice * 64;
#pragma unroll 4
    for (int i = 0; i < 64; ++i) {
        float4 t = tg[base + i];
        int j = jbase + i;
#pragma unroll
        for (int k = 0; k < 8; ++k) {
            float s = fmaf(-sx[k], t.x, fmaf(-sy[k], t.y, fmaf(-sz[k], t.z, t.w)));
            if (s < sm[k]) { sm[k] = s; jm[k] = j; }   // ascending j: first-min
        }
    }
#pragma unroll
    for (int k = 0; k < 8; ++k)
        comb[slice][g * 8 + k] = make_float2(sm[k], __int_as_float(jm[k]));
    __syncthreads();

    // wave 0: merge 32 slices (ascending => exact tie-break), fp64 contributions
    if (tid < 64) {
        float fb = INFINITY; int fj = 0;
#pragma unroll 8
        for (int q = 0; q < 32; ++q) {
            float2 e = comb[q][tid];
            if (e.x < fb) { fb = e.x; fj = __float_as_int(e.y); }
        }
        float4 P = ps[tid];
        float d2 = fmaf(2.0f, fb, P.w);
        float dist = sqrtf(fmaxf(d2, EPSF));
        float4 Q = tg[fj + (fj >> 6)];

        double v[16];
        v[0] = dist;
        v[1] = P.x; v[2] = P.y; v[3] = P.z;
        v[4] = Q.x; v[5] = Q.y; v[6] = Q.z;
        v[7]  = (double)P.x * Q.x; v[8]  = (double)P.x * Q.y; v[9]  = (double)P.x * Q.z;
        v[10] = (double)P.y * Q.x; v[11] = (double)P.y * Q.y; v[12] = (double)P.y * Q.z;
        v[13] = (double)P.z * Q.x; v[14] = (double)P.z * Q.y; v[15] = (double)P.z * Q.z;
#pragma unroll
        for (int k = 0; k < 16; ++k) {
            double x = v[k];
#pragma unroll
            for (int off = 32; off > 0; off >>= 1) x += __shfl_down(x, off);
            v[k] = x;
        }
        if (tid == 0) {
            // LLC-visible stores (sc-bypass), no L2 flush needed
            double* dst = partial + blk * 16;
#pragma unroll
            for (int k = 0; k < 16; ++k)
                __hip_atomic_store(dst + k, v[k], __ATOMIC_RELAXED,
                                   __HIP_MEMORY_SCOPE_AGENT);
            // ensure stores completed at the coherence point, then take a ticket
            asm volatile("s_waitcnt vmcnt(0)" ::: "memory");
            unsigned old = __hip_atomic_fetch_add(&ticket[it], 1u,
                                                  __ATOMIC_RELAXED,
                                                  __HIP_MEMORY_SCOPE_AGENT);
            lastflag = (old == GRID_ITER - 1) ? 1 : 0;
        }
    }
    __syncthreads();
    if (!lastflag) return;

    // ================= tail (single last block) =================
    {
        int tb2 = tid >> 5;          // batch (0..7)
        int c32 = tid & 31;          // which chunk-partial
        double acc[16];
        const double* pp2 = partial + (tb2 * 32 + c32) * 16;
#pragma unroll
        for (int k = 0; k < 16; ++k)
            acc[k] = __hip_atomic_load(pp2 + k, __ATOMIC_RELAXED,
                                       __HIP_MEMORY_SCOPE_AGENT);
#pragma unroll
        for (int k = 0; k < 16; ++k) {
            double x = acc[k];
            x += __shfl_down(x, 16);
            x += __shfl_down(x, 8);
            x += __shfl_down(x, 4);
            x += __shfl_down(x, 2);
            x += __shfl_down(x, 1);
            if (c32 == 0) sred[tb2][k] = x;
        }
    }
    __syncthreads();

    if (tid < 64) {
        double s[16];
        float errnew = 0.0f;
        bool conv = true;
        if (tid < NB) {
#pragma unroll
            for (int k = 0; k < 16; ++k) s[k] = sred[tid][k];
            errnew = (float)(s[0] * (1.0 / (double)NP));
            conv = fabsf(errnew - err[tid]) < TOLF;
        }
        unsigned long long mm = __ballot(conv);
        int done_new = ((mm & 0xFFull) == 0xFFull) ? 1 : 0;
        if (tid == 0 && done_new) *done = 1;

        if (tid < NB) {
            double* T = Tc + tid * 12;
            double To[12];
#pragma unroll
            for (int k = 0; k < 12; ++k) To[k] = T[k];

            if (!done_new) {
                err[tid] = errnew;
                double R[9], t[3];
                kabsch3x3(&s[7], &s[1], &s[4], R, t);
                double Rn[12];
#pragma unroll
                for (int i = 0; i < 3; ++i) {
#pragma unroll
                    for (int j = 0; j < 3; ++j)
                        Rn[i * 3 + j] = R[i * 3 + 0] * To[0 + j]
                                      + R[i * 3 + 1] * To[3 + j]
                                      + R[i * 3 + 2] * To[6 + j];
                    Rn[9 + i] = R[i * 3 + 0] * To[9] + R[i * 3 + 1] * To[10]
                              + R[i * 3 + 2] * To[11] + t[i];
                }
                float* F = TcF + tid * 12;
#pragma unroll
                for (int k = 0; k < 12; ++k) { T[k] = Rn[k]; F[k] = (float)Rn[k]; To[k] = Rn[k]; }
            }

            // out = current cumulative transform (Kabsch(psrc, T(psrc)) == T)
            float* o = out + tid * 12;
#pragma unroll
            for (int i = 0; i < 3; ++i) {
#pragma unroll
                for (int j = 0; j < 3; ++j) o[i * 4 + j] = (float)To[i * 3 + j];
                o[i * 4 + 3] = (float)To[9 + i];
            }
        }
    }
}

extern "C" void kernel_launch(void* const* d_in, const int* in_sizes, int n_in,
                              void* d_out, int out_size, void* d_ws, size_t ws_size,
                              hipStream_t stream) {
    const float* psrc = (const float*)d_in[0];
    const float* ptgt = (const float*)d_in[1];
    float* out = (float*)d_out;

    char* ws = (char*)d_ws;
    size_t off = 0;
    double* partial = (double*)(ws + off); off += (size_t)GRID_ITER * 16 * sizeof(double); // 32KB
    double* Tc   = (double*)(ws + off); off += NB * 12 * sizeof(double);
    float*  TcF  = (float*)(ws + off);  off += NB * 12 * sizeof(float);
    float*  err  = (float*)(ws + off);  off += 32;
    int*    done = (int*)(ws + off);    off += 16;
    unsigned int* ticket = (unsigned int*)(ws + off);

    icp_init<<<1, 256, 0, stream>>>(Tc, TcF, err, done, ticket);

    for (int it = 0; it < 10; ++it) {
        icp_iter<<<GRID_ITER, 256, 0, stream>>>(psrc, ptgt, partial, Tc, TcF,
                                                err, done, ticket, out, it);
    }
}

// Round 9
// 236.664 us; speedup vs baseline: 2.4170x; 1.0978x over previous
//
#include <hip/hip_runtime.h>
#include <math.h>

#define NB 8
#define NP 2048
#define GRID 256        // 8 batches * 32 src-chunks of 64; <=1-2 blocks/CU => co-resident
#define TOLF 1e-4f
#define EPSF 1e-12f

#define AL(p)   __hip_atomic_load((p), __ATOMIC_RELAXED, __HIP_MEMORY_SCOPE_AGENT)
#define AS(p,v) __hip_atomic_store((p), (v), __ATOMIC_RELAXED, __HIP_MEMORY_SCOPE_AGENT)

// identical fmaf structure everywhere => bit-identical transformed points
__device__ inline float3 xform_pt(const float* __restrict__ T,
                                  float x, float y, float z) {
    float3 r;
    r.x = fmaf(T[0], x, fmaf(T[1], y, fmaf(T[2], z, T[9])));
    r.y = fmaf(T[3], x, fmaf(T[4], y, fmaf(T[5], z, T[10])));
    r.z = fmaf(T[6], x, fmaf(T[7], y, fmaf(T[8], z, T[11])));
    return r;
}

// ---------------- 3x3 Kabsch (double, one-sided Jacobi SVD) ----------------
__device__ void kabsch3x3(const double Spq[9], const double Sp[3], const double Sq[3],
                          double R[9], double t[3]) {
    const double invN = 1.0 / (double)NP;
    double cs[3], ct[3];
#pragma unroll
    for (int i = 0; i < 3; ++i) { cs[i] = Sp[i] * invN; ct[i] = Sq[i] * invN; }
    double H[9];
#pragma unroll
    for (int i = 0; i < 3; ++i)
#pragma unroll
        for (int j = 0; j < 3; ++j)
            H[i * 3 + j] = Spq[i * 3 + j] - (double)NP * cs[i] * ct[j];

    double Bc[3][3], V[3][3];
#pragma unroll
    for (int j = 0; j < 3; ++j)
#pragma unroll
        for (int i = 0; i < 3; ++i) {
            Bc[j][i] = H[i * 3 + j];
            V[j][i]  = (i == j) ? 1.0 : 0.0;
        }
    for (int sweep = 0; sweep < 16; ++sweep) {
        bool rotated = false;
        for (int p = 0; p < 2; ++p)
            for (int q = p + 1; q < 3; ++q) {
                double app = 0, aqq = 0, apq = 0;
#pragma unroll
                for (int i = 0; i < 3; ++i) {
                    app += Bc[p][i] * Bc[p][i];
                    aqq += Bc[q][i] * Bc[q][i];
                    apq += Bc[p][i] * Bc[q][i];
                }
                if (apq * apq > 1e-60 + 1e-28 * app * aqq) {
                    rotated = true;
                    double tau = (aqq - app) / (2.0 * apq);
                    double tt  = (tau >= 0 ? 1.0 : -1.0) / (fabs(tau) + sqrt(1.0 + tau * tau));
                    double c   = 1.0 / sqrt(1.0 + tt * tt);
                    double sn  = c * tt;
#pragma unroll
                    for (int i = 0; i < 3; ++i) {
                        double bp = Bc[p][i], bq = Bc[q][i];
                        Bc[p][i] = c * bp - sn * bq;
                        Bc[q][i] = sn * bp + c * bq;
                        double vp = V[p][i], vq = V[q][i];
                        V[p][i] = c * vp - sn * vq;
                        V[q][i] = sn * vp + c * vq;
                    }
                }
            }
        if (!rotated) break;
    }
    double sv[3], U[3][3];
#pragma unroll
    for (int j = 0; j < 3; ++j) {
        sv[j] = sqrt(Bc[j][0] * Bc[j][0] + Bc[j][1] * Bc[j][1] + Bc[j][2] * Bc[j][2]);
        double inv = sv[j] > 0.0 ? 1.0 / sv[j] : 0.0;
#pragma unroll
        for (int i = 0; i < 3; ++i) U[j][i] = Bc[j][i] * inv;
    }
    double detH = H[0] * (H[4] * H[8] - H[5] * H[7])
                - H[1] * (H[3] * H[8] - H[5] * H[6])
                + H[2] * (H[3] * H[7] - H[4] * H[6]);
    double d = (detH >= 0.0) ? 1.0 : -1.0;
    int o[3] = {0, 1, 2};
    if (sv[o[0]] < sv[o[1]]) { int tmp = o[0]; o[0] = o[1]; o[1] = tmp; }
    if (sv[o[0]] < sv[o[2]]) { int tmp = o[0]; o[0] = o[2]; o[2] = tmp; }
    if (sv[o[1]] < sv[o[2]]) { int tmp = o[1]; o[1] = o[2]; o[2] = tmp; }
    double sg[3] = {1.0, 1.0, d};
#pragma unroll
    for (int i = 0; i < 3; ++i)
#pragma unroll
        for (int j = 0; j < 3; ++j) {
            double acc = 0.0;
#pragma unroll
            for (int k = 0; k < 3; ++k) acc += sg[k] * V[o[k]][i] * U[o[k]][j];
            R[i * 3 + j] = acc;
        }
#pragma unroll
    for (int i = 0; i < 3; ++i)
        t[i] = ct[i] - (R[i * 3 + 0] * cs[0] + R[i * 3 + 1] * cs[1] + R[i * 3 + 2] * cs[2]);
}

// ---------------- init: reset barrier state ----------------
__global__ __launch_bounds__(256) void icp_init(unsigned* __restrict__ flags,
                                                unsigned* __restrict__ epoch) {
    flags[threadIdx.x] = 0u;
    if (threadIdx.x == 0) *epoch = 0u;
}

// ---------------- the whole ICP: one persistent kernel ----------------
// grid: 256 blocks = batch(8) x src-chunk(32 of 64 pts), 256 threads.
// Cross-block comm: agent-scope (LLC) atomics + per-wave vmcnt(0). No fences,
// no L2 flushes. Block 0 owns all scalar state (Tc, err) in its LDS.
__global__ __launch_bounds__(256, 2) void icp_all(
        const float* __restrict__ psrc, const float* __restrict__ ptgt,
        float* __restrict__ out,
        double* __restrict__ partial,    // [256][16]
        float* __restrict__ TcF,         // [8][12] published transform
        unsigned* __restrict__ flags,    // [256] per-block arrival (monotone it+1)
        unsigned* __restrict__ epoch) {  // low31 = completed iters, bit31 = done
    __shared__ float4 tg[2080];          // targets, padded: idx = j + (j>>6)
    __shared__ float4 ps[64];            // transformed src pts (x,y,z,|P|^2)
    __shared__ float2 comb[32][66];      // [slice][src] winners
    __shared__ double sred[NB][16];
    __shared__ float  TcL[12];           // this batch's current transform
    __shared__ double TcA[NB][12];       // block 0 only: cumulative fp64
    __shared__ float  errL[NB];          // block 0 only
    __shared__ int    sh_done;

    const int tid   = threadIdx.x;
    const int blk   = blockIdx.x;
    const int b     = blk >> 5;          // batch
    const int sc    = blk & 31;          // src chunk
    const int slice = tid & 31;          // target slice (64 targets)
    const int g     = tid >> 5;          // src group (8 pts)

    // stage all 2048 targets once (reused by all 10 iterations)
    const float* tb = ptgt + b * NP * 3;
    for (int j = tid; j < NP; j += 256) {
        float tx = tb[3 * j + 0], ty = tb[3 * j + 1], tz = tb[3 * j + 2];
        tg[j + (j >> 6)] = make_float4(tx, ty, tz,
                                       0.5f * (tx * tx + ty * ty + tz * tz));
    }
    if (tid < 12) TcL[tid] = (tid == 0 || tid == 4 || tid == 8) ? 1.0f : 0.0f;
    if (blk == 0) {
        if (tid < NB) errL[tid] = 0.0f;
        if (tid < 96) {
            int r = tid % 12;
            TcA[tid / 12][r] = (r == 0 || r == 4 || r == 8) ? 1.0 : 0.0;
        }
    }
    __syncthreads();

    for (int it = 0; it < 10; ++it) {
        // ---- transform this chunk's 64 src points with current TcL ----
        if (tid < 64) {
            const float* pp = psrc + (b * NP + sc * 64 + tid) * 3;
            float3 P = xform_pt(TcL, pp[0], pp[1], pp[2]);
            ps[tid] = make_float4(P.x, P.y, P.z,
                                  P.x * P.x + P.y * P.y + P.z * P.z);
        }
        __syncthreads();

        // ---- NN: 8 src pts/thread x 64 targets of this slice ----
        float sx[8], sy[8], sz[8], sm[8];
        int jm[8];
#pragma unroll
        for (int k = 0; k < 8; ++k) {
            float4 P = ps[g * 8 + k];
            sx[k] = P.x; sy[k] = P.y; sz[k] = P.z;
            sm[k] = INFINITY; jm[k] = 0;
        }
        const int base = slice * 65, jbase = slice * 64;
#pragma unroll 4
        for (int i = 0; i < 64; ++i) {
            float4 t = tg[base + i];
            int j = jbase + i;
#pragma unroll
            for (int k = 0; k < 8; ++k) {
                float s = fmaf(-sx[k], t.x, fmaf(-sy[k], t.y, fmaf(-sz[k], t.z, t.w)));
                if (s < sm[k]) { sm[k] = s; jm[k] = j; }   // ascending j: first-min
            }
        }
#pragma unroll
        for (int k = 0; k < 8; ++k)
            comb[slice][g * 8 + k] = make_float2(sm[k], __int_as_float(jm[k]));
        __syncthreads();

        // ---- wave 0: merge slices (ascending => exact tie-break), fp64 sums ----
        if (tid < 64) {
            float fb = INFINITY; int fj = 0;
#pragma unroll 8
            for (int q = 0; q < 32; ++q) {
                float2 e = comb[q][tid];
                if (e.x < fb) { fb = e.x; fj = __float_as_int(e.y); }
            }
            float4 P = ps[tid];
            float d2 = fmaf(2.0f, fb, P.w);
            float dist = sqrtf(fmaxf(d2, EPSF));
            float4 Q = tg[fj + (fj >> 6)];

            double v[16];
            v[0] = dist;
            v[1] = P.x; v[2] = P.y; v[3] = P.z;
            v[4] = Q.x; v[5] = Q.y; v[6] = Q.z;
            v[7]  = (double)P.x * Q.x; v[8]  = (double)P.x * Q.y; v[9]  = (double)P.x * Q.z;
            v[10] = (double)P.y * Q.x; v[11] = (double)P.y * Q.y; v[12] = (double)P.y * Q.z;
            v[13] = (double)P.z * Q.x; v[14] = (double)P.z * Q.y; v[15] = (double)P.z * Q.z;
#pragma unroll
            for (int k = 0; k < 16; ++k) {
                double x = v[k];
#pragma unroll
                for (int off = 32; off > 0; off >>= 1) x += __shfl_down(x, off);
                v[k] = x;
            }
            if (tid == 0) {
                double* dst = partial + blk * 16;
#pragma unroll
                for (int k = 0; k < 16; ++k) AS(dst + k, v[k]);
                // partials at LLC before arrival flag
                asm volatile("s_waitcnt vmcnt(0)" ::: "memory");
                AS(&flags[blk], (unsigned)(it + 1));
            }
        }

        // ---- block 0: wait all 256 arrivals, reduce, Kabsch, publish ----
        if (blk == 0) {
            if (tid < 64) {
                bool ok;
                do {
                    ok = true;
#pragma unroll
                    for (int q = 0; q < 4; ++q)
                        ok = ok && (AL(&flags[tid * 4 + q]) >= (unsigned)(it + 1));
                    if (!__all(ok)) __builtin_amdgcn_s_sleep(1); else break;
                } while (true);
            }
            __syncthreads();
            {
                int tb2 = tid >> 5;          // batch
                int c32 = tid & 31;          // chunk-partial
                double acc[16];
                const double* pp2 = partial + (tb2 * 32 + c32) * 16;
#pragma unroll
                for (int k = 0; k < 16; ++k) acc[k] = AL(pp2 + k);
#pragma unroll
                for (int k = 0; k < 16; ++k) {
                    double x = acc[k];
                    x += __shfl_down(x, 16);
                    x += __shfl_down(x, 8);
                    x += __shfl_down(x, 4);
                    x += __shfl_down(x, 2);
                    x += __shfl_down(x, 1);
                    if (c32 == 0) sred[tb2][k] = x;
                }
            }
            __syncthreads();
            if (tid < 64) {
                double s[16];
                float errnew = 0.0f;
                bool conv = true;
                if (tid < NB) {
#pragma unroll
                    for (int k = 0; k < 16; ++k) s[k] = sred[tid][k];
                    errnew = (float)(s[0] * (1.0 / (double)NP));
                    conv = fabsf(errnew - errL[tid]) < TOLF;
                }
                unsigned long long mm = __ballot(conv);
                int done_new = ((mm & 0xFFull) == 0xFFull) ? 1 : 0;
                if (tid == 0) sh_done = done_new;
                if (tid < NB && !done_new) {
                    errL[tid] = errnew;
                    double R[9], t[3];
                    kabsch3x3(&s[7], &s[1], &s[4], R, t);
                    double To[12];
#pragma unroll
                    for (int k = 0; k < 12; ++k) To[k] = TcA[tid][k];
#pragma unroll
                    for (int i = 0; i < 3; ++i) {
#pragma unroll
                        for (int j = 0; j < 3; ++j)
                            TcA[tid][i * 3 + j] = R[i * 3 + 0] * To[0 + j]
                                                + R[i * 3 + 1] * To[3 + j]
                                                + R[i * 3 + 2] * To[6 + j];
                        TcA[tid][9 + i] = R[i * 3 + 0] * To[9] + R[i * 3 + 1] * To[10]
                                        + R[i * 3 + 2] * To[11] + t[i];
                    }
                }
            }
            __syncthreads();
            if (tid < 96) AS(&TcF[tid], (float)TcA[tid / 12][tid % 12]);
            asm volatile("s_waitcnt vmcnt(0)" ::: "memory");
            __syncthreads();
            if (tid == 0)
                AS(epoch, (unsigned)(it + 1) | (sh_done ? 0x80000000u : 0u));
        }

        // ---- all blocks: wait epoch, read done bit ----
        if (tid == 0) {
            unsigned e;
            while (((e = AL(epoch)) & 0x7FFFFFFFu) < (unsigned)(it + 1))
                __builtin_amdgcn_s_sleep(1);
            sh_done = (int)(e >> 31);
        }
        __syncthreads();
        if (sh_done) break;
        if (tid < 12) TcL[tid] = AL(&TcF[b * 12 + tid]);
        __syncthreads();
    }

    // ---- output (block 0; Kabsch(psrc, T(psrc)) == T exactly) ----
    if (blk == 0 && tid < NB) {
        float* o = out + tid * 12;
#pragma unroll
        for (int i = 0; i < 3; ++i) {
#pragma unroll
            for (int j = 0; j < 3; ++j) o[i * 4 + j] = (float)TcA[tid][i * 3 + j];
            o[i * 4 + 3] = (float)TcA[tid][9 + i];
        }
    }
}

extern "C" void kernel_launch(void* const* d_in, const int* in_sizes, int n_in,
                              void* d_out, int out_size, void* d_ws, size_t ws_size,
                              hipStream_t stream) {
    const float* psrc = (const float*)d_in[0];
    const float* ptgt = (const float*)d_in[1];
    float* out = (float*)d_out;

    char* ws = (char*)d_ws;
    size_t off = 0;
    double* partial = (double*)(ws + off); off += (size_t)GRID * 16 * sizeof(double); // 32KB
    float*  TcF  = (float*)(ws + off);     off += NB * 12 * sizeof(float);
    unsigned* flags = (unsigned*)(ws + off); off += GRID * sizeof(unsigned);
    unsigned* epoch = (unsigned*)(ws + off); off += 16;

    icp_init<<<1, 256, 0, stream>>>(flags, epoch);
    icp_all<<<GRID, 256, 0, stream>>>(psrc, ptgt, out, partial, TcF, flags, epoch);
}